// Round 4
// baseline (288.606 us; speedup 1.0000x reference)
//
#include <hip/hip_runtime.h>
#include <stdint.h>

#define N_TOK 64
#define K_DIM 4096
#define N_OUT 11008
#define LUT_N 256
#define IDX_ELEMS (N_OUT * K_DIM)  // 45,088,768

typedef __attribute__((ext_vector_type(4))) float  floatx4;
typedef __attribute__((ext_vector_type(8))) __bf16 bf16x8;

__device__ __forceinline__ unsigned bf16_rne(float f) {
  unsigned u = __builtin_bit_cast(unsigned, f);
  return (u + 0x7fffu + ((u >> 16) & 1u)) >> 16;  // round-nearest-even to bf16
}

// ---- pass 1a: idx int32 -> uint8, pure sequential stream (DRAM-friendly) ----
// 16 idx per thread-iter: 64 B in (4x dwordx4), 16 B out (1x dwordx4).
__global__ __launch_bounds__(256) void repack_kernel(const int* __restrict__ gi,
                                                     uint8_t* __restrict__ g8) {
  const int nt = gridDim.x * 256;
  for (int g = blockIdx.x * 256 + threadIdx.x; g < IDX_ELEMS / 16; g += nt) {
    const int4* p = (const int4*)gi + (size_t)g * 4;
    int4 a = p[0], b = p[1], c = p[2], d = p[3];
    uint4 o;
    o.x = (unsigned)a.x | ((unsigned)a.y << 8) | ((unsigned)a.z << 16) | ((unsigned)a.w << 24);
    o.y = (unsigned)b.x | ((unsigned)b.y << 8) | ((unsigned)b.z << 16) | ((unsigned)b.w << 24);
    o.z = (unsigned)c.x | ((unsigned)c.y << 8) | ((unsigned)c.z << 16) | ((unsigned)c.w << 24);
    o.w = (unsigned)d.x | ((unsigned)d.y << 8) | ((unsigned)d.z << 16) | ((unsigned)d.w << 24);
    *(uint4*)(g8 + (size_t)g * 16) = o;
  }
}

// ---- pass 1b: pack x (fp32 [64][4096]) into A-fragment-ordered bf16 ----
// chunk c = kstep*4 + tt, kstep in [0,128); lane (q,m15) holds 8 bf16:
//   x[(tt*16+m15)*4096 + kstep*32 + q*8 + j]
__global__ __launch_bounds__(256) void xpack_kernel(const float* __restrict__ x,
                                                    uint32_t* __restrict__ xp) {
  const int t = blockIdx.x * 256 + threadIdx.x;  // [0, 32768)
  const int lane = t & 63, c = t >> 6;
  const int m15 = lane & 15, q = lane >> 4;
  const int tt = c & 3, kstep = c >> 2;
  const int src = (tt * 16 + m15) * K_DIM + kstep * 32 + q * 8;
  float4 a = *(const float4*)(x + src);
  float4 b = *(const float4*)(x + src + 4);
  uint4 o;
  o.x = bf16_rne(a.x) | (bf16_rne(a.y) << 16);
  o.y = bf16_rne(a.z) | (bf16_rne(a.w) << 16);
  o.z = bf16_rne(b.x) | (bf16_rne(b.y) << 16);
  o.w = bf16_rne(b.z) | (bf16_rne(b.w) << 16);
  *(uint4*)(xp + (size_t)t * 4) = o;
}

// ---- pass 2: the linear. idx (uint8) is LLC-resident from pass 1a. ----
// block: 16 output features, 4 waves; wave w owns K in [w*1024,(w+1)*1024),
// 32 K-steps of 32. Barrier-free K-loop; both streams register-pipelined depth 4.
// MFMA 16x16x32 bf16: A[m=lane&15][k=q*8+j], B[k=q*8+j][n=lane&15];
// C/D: row(token)=q*4+reg, col(feature)=lane&15.
__global__ __launch_bounds__(256, 3) void ghost_kernel(
    const uint8_t* __restrict__ g8, const float* __restrict__ lut,
    const float* __restrict__ scale, const uint32_t* __restrict__ xp,
    float* __restrict__ out) {
  __shared__ uint32_t lut_lds[LUT_N * 16];  // 16 bank-strided copies, bf16 in low16
  __shared__ floatx4 red[4][4][64];         // 16 KB cross-wave reduction buffer

  const int tid = threadIdx.x;
  {  // replicated LUT: copy c at dword [v*16+c]; lane uses copy lane&15
    unsigned hb = bf16_rne(lut[tid]);
#pragma unroll
    for (int c = 0; c < 16; ++c) lut_lds[tid * 16 + c] = hb;
  }
  __syncthreads();

  const int w = tid >> 6, lane = tid & 63;
  const int m15 = lane & 15, q = lane >> 4;
  const int o = blockIdx.x * 16 + m15;

  // idx bytes: step st -> row o, cols w*1024 + st*32 + q*8 .. +7 (8 bytes)
  const uint8_t* ip = g8 + (size_t)o * K_DIM + w * 1024 + q * 8;
  const uint4* ap4 = (const uint4*)xp;

  floatx4 acc[4];
#pragma unroll
  for (int tt = 0; tt < 4; ++tt) acc[tt] = (floatx4){0.f, 0.f, 0.f, 0.f};

  uint2 ib[4];     // idx pipeline, depth 4 (8 idx bytes per step)
  uint4 ab[4][4];  // A pipeline, depth 4 x 4 token-tiles
#pragma unroll
  for (int p = 0; p < 4; ++p) {
    ib[p] = *(const uint2*)(ip + p * 32);
#pragma unroll
    for (int tt = 0; tt < 4; ++tt)
      ab[p][tt] = ap4[(size_t)(((w * 32 + p) * 4 + tt)) * 64 + lane];
  }

#pragma unroll 4
  for (int st = 0; st < 32; ++st) {
    const int p = st & 3;
    const uint2 iv = ib[p];
    uint4 a0 = ab[p][0], a1 = ab[p][1], a2 = ab[p][2], a3 = ab[p][3];
    if (st < 28) {  // prefetch step st+4 (issued before any dependent use)
      ib[p] = *(const uint2*)(ip + (st + 4) * 32);
#pragma unroll
      for (int tt = 0; tt < 4; ++tt)
        ab[p][tt] = ap4[(size_t)(((w * 32 + st + 4) * 4 + tt)) * 64 + lane];
    }

    // byte-extract + LUT gathers: dword addr v*16+m15 -> <=2 lanes/bank (free)
    unsigned g0 = lut_lds[(iv.x & 0xFFu) * 16 + m15];
    unsigned g1 = lut_lds[((iv.x >> 8) & 0xFFu) * 16 + m15];
    unsigned g2 = lut_lds[((iv.x >> 16) & 0xFFu) * 16 + m15];
    unsigned g3 = lut_lds[(iv.x >> 24) * 16 + m15];
    unsigned g4 = lut_lds[(iv.y & 0xFFu) * 16 + m15];
    unsigned g5 = lut_lds[((iv.y >> 8) & 0xFFu) * 16 + m15];
    unsigned g6 = lut_lds[((iv.y >> 16) & 0xFFu) * 16 + m15];
    unsigned g7 = lut_lds[(iv.y >> 24) * 16 + m15];
    uint4 bi;
    bi.x = __builtin_amdgcn_perm(g1, g0, 0x05040100u);  // [bf16(k0)|bf16(k1)<<16]
    bi.y = __builtin_amdgcn_perm(g3, g2, 0x05040100u);
    bi.z = __builtin_amdgcn_perm(g5, g4, 0x05040100u);
    bi.w = __builtin_amdgcn_perm(g7, g6, 0x05040100u);
    const bf16x8 bfrag = __builtin_bit_cast(bf16x8, bi);

    acc[0] = __builtin_amdgcn_mfma_f32_16x16x32_bf16(
        __builtin_bit_cast(bf16x8, a0), bfrag, acc[0], 0, 0, 0);
    acc[1] = __builtin_amdgcn_mfma_f32_16x16x32_bf16(
        __builtin_bit_cast(bf16x8, a1), bfrag, acc[1], 0, 0, 0);
    acc[2] = __builtin_amdgcn_mfma_f32_16x16x32_bf16(
        __builtin_bit_cast(bf16x8, a2), bfrag, acc[2], 0, 0, 0);
    acc[3] = __builtin_amdgcn_mfma_f32_16x16x32_bf16(
        __builtin_bit_cast(bf16x8, a3), bfrag, acc[3], 0, 0, 0);
  }

  // ---- cross-wave K reduction + scale + store ----
  __syncthreads();
#pragma unroll
  for (int tt = 0; tt < 4; ++tt) red[w][tt][lane] = acc[tt];
  __syncthreads();
  {
    floatx4 r = red[0][w][lane];
    r += red[1][w][lane];
    r += red[2][w][lane];
    r += red[3][w][lane];
    const float sc = scale[blockIdx.x * 16 + m15];
    r *= sc;
#pragma unroll
    for (int i = 0; i < 4; ++i)
      out[(size_t)(16 * w + q * 4 + i) * N_OUT + blockIdx.x * 16 + m15] = r[i];
  }
}

extern "C" void kernel_launch(void* const* d_in, const int* in_sizes, int n_in,
                              void* d_out, int out_size, void* d_ws, size_t ws_size,
                              hipStream_t stream) {
  const float* x   = (const float*)d_in[0];
  const int*   gi  = (const int*)d_in[1];
  const float* lut = (const float*)d_in[2];
  const float* sc  = (const float*)d_in[3];
  float*       out = (float*)d_out;

  // ws layout: [0, 45 MB) uint8 idx ; [45 MB, +512 KB) packed-A bf16
  uint8_t*  g8 = (uint8_t*)d_ws;
  uint32_t* xp = (uint32_t*)((uint8_t*)d_ws + (size_t)IDX_ELEMS);

  xpack_kernel<<<(N_TOK * K_DIM / 8) / 256, 256, 0, stream>>>(x, xp);
  repack_kernel<<<2048, 256, 0, stream>>>(gi, g8);
  ghost_kernel<<<N_OUT / 16, 256, 0, stream>>>(g8, lut, sc, xp, out);
}